// Round 12
// baseline (49.067 us; speedup 1.0000x reference)
//
#include <hip/hip_runtime.h>
#include <math.h>

#define B_N 65536
#define C_N 100
constexpr float ALPHA = 0.01f;
constexpr float TAU   = 2.0f;
constexpr float TEMP  = 2.0f;
constexpr float EPSF  = 1e-9f;
constexpr float NEG_SENT = -1.0e30f;   // sentinel: exp -> 0, finite

typedef float v2f __attribute__((ext_vector_type(2)));
typedef float v4f __attribute__((ext_vector_type(4)));

// ---------------- DPP reduction helpers (VALU-only) ----------------
// After rowsum32, all lanes with (lane&31)>=16 hold the 32-group total.
template<int CTRL>
__device__ __forceinline__ float fadd_dpp(float x) {
    return x + __int_as_float(__builtin_amdgcn_update_dpp(
        0, __float_as_int(x), CTRL, 0xF, 0xF, true));
}
__device__ __forceinline__ float rowsum32(float x) {
    x = fadd_dpp<0xB1>(x);    // quad_perm xor1
    x = fadd_dpp<0x4E>(x);    // quad_perm xor2
    x = fadd_dpp<0x124>(x);   // row_ror:4
    x = fadd_dpp<0x128>(x);   // row_ror:8
    x = fadd_dpp<0x142>(x);   // row_bcast15
    return x;
}
template<int CTRL>
__device__ __forceinline__ void amax_dpp(unsigned &hi, unsigned &lo) {
    const unsigned yh = (unsigned)__builtin_amdgcn_update_dpp(0, (int)hi, CTRL, 0xF, 0xF, true);
    const unsigned yl = (unsigned)__builtin_amdgcn_update_dpp(0, (int)lo, CTRL, 0xF, 0xF, true);
    const bool take = (yh > hi) || (yh == hi && yl > lo);
    hi = take ? yh : hi;
    lo = take ? yl : lo;
}
__device__ __forceinline__ void rowamax32(unsigned &hi, unsigned &lo) {
    amax_dpp<0xB1>(hi, lo);
    amax_dpp<0x4E>(hi, lo);
    amax_dpp<0x124>(hi, lo);
    amax_dpp<0x128>(hi, lo);
    amax_dpp<0x142>(hi, lo);
}

__device__ __forceinline__ float wsum(float v) {
    #pragma unroll
    for (int o = 32; o; o >>= 1) v += __shfl_xor(v, o);
    return v;
}

// ---------- prep: bincount (0-255) + prior tables (256) + cos softmax (257-260) ----------
__global__ void prep_k(const float* __restrict__ cosf, const float* __restrict__ prior,
                       const int* __restrict__ target,
                       float* __restrict__ sm, float* __restrict__ w2,
                       float* __restrict__ w3, float* __restrict__ Ht,
                       int* __restrict__ counts) {
    const int b = blockIdx.x;
    if (b < 256) {
        __shared__ int h[C_N];
        for (int i = threadIdx.x; i < C_N; i += blockDim.x) h[i] = 0;
        __syncthreads();
        const int gid = b * blockDim.x + threadIdx.x;
        const int stride = 256 * blockDim.x;
        for (int i = gid; i < B_N; i += stride) atomicAdd(&h[target[i]], 1);
        __syncthreads();
        for (int i = threadIdx.x; i < C_N; i += blockDim.x)
            if (h[i]) atomicAdd(&counts[i], h[i]);
    } else if (b == 256) {
        __shared__ float sp[C_N];
        __shared__ float val[C_N];
        const int t = threadIdx.x;
        if (t < C_N) sp[t] = prior[t];
        __syncthreads();
        int rank = 0;
        float lpi = 0.f, pi = 0.f;
        if (t < C_N) {
            pi = sp[t];
            for (int j = 0; j < C_N; ++j) {
                const float pj = sp[j];
                rank += (pj < pi) || (pj == pi && j < t);   // stable argsort rank
            }
            val[rank] = pi;
            lpi = __logf(pi + EPSF);
        }
        __syncthreads();
        if (t < C_N) {
            const float inv = val[C_N - 1 - rank];
            const float c3v = lpi - TAU * __logf(inv + EPSF);
            w2[t] = pi + EPSF;          // exp(e2+lp) = w2*exp(e2)
            w3[t] = __expf(c3v);        // exp(e3+c3) = w3*exp(e3)
            Ht[t] = lpi + c3v;          // lp+c3, for the label dot
        }
    } else {
        const int gw = (b - 257) * 4 + (threadIdx.x >> 6);   // 0..15
        const int lane = threadIdx.x & 63;
        for (int row = gw; row < C_N; row += 16) {
            const float* rp = cosf + row * C_N;
            const float v0 = rp[lane];
            const bool has1 = (lane + 64) < C_N;
            const float v1 = has1 ? rp[lane + 64] : -INFINITY;
            float m = fmaxf(v0, v1);
            #pragma unroll
            for (int o = 32; o; o >>= 1) m = fmaxf(m, __shfl_xor(m, o));
            const float e0 = __expf(v0 - m);
            const float e1 = has1 ? __expf(v1 - m) : 0.f;
            const float s = wsum(e0 + e1);
            const float is = 1.0f / s;
            sm[row * C_N + lane] = e0 * is;
            if (has1) sm[row * C_N + lane + 64] = e1 * is;
        }
    }
}

// ---------- main: role-interleaved blocks, NT loads + NT stores, bucket partials ----------
#define HBLK 4096
#define NBLK (2 * HBLK)

__launch_bounds__(256, 8)
__global__ void main_k(const int* __restrict__ target,
                       const float* __restrict__ e1p, const float* __restrict__ e2p,
                       const float* __restrict__ e3p, const float* __restrict__ opp,
                       const float* __restrict__ outp,
                       const float* __restrict__ sm, const float* __restrict__ w2p,
                       const float* __restrict__ w3p, const float* __restrict__ Hp,
                       const int* __restrict__ counts,
                       float* __restrict__ dout,
                       float* __restrict__ pl, float* __restrict__ pk, float* __restrict__ pn) {
    const int lane = threadIdx.x & 63;
    const int gl   = lane & 31;
    const int half = lane >> 5;
    const int wslot = threadIdx.x >> 6;
    const bool act = gl < 25;
    const int c0 = 4 * gl;
    const bool own = (gl == 16);
    __shared__ float bl[4], bk[4], bn[4];
    const int role = blockIdx.x & 1;
    const int j    = blockIdx.x >> 1;
    const int bucket = blockIdx.x & 255;

    if (role == 0) {
        // ================= CE role: e1,e2,e3 + sm gather -> loss partial =================
        const int gw = j * 4 + wslot;
        const int rowA = 4 * gw + half;
        const int rowB = 4 * gw + 2 + half;
        const int tgtA = target[rowA];
        const int tgtB = target[rowB];
        const int baseA = rowA * C_N;
        const int baseB = rowB * C_N;

        float4 W2 = make_float4(0,0,0,0), W3 = make_float4(0,0,0,0), HH = make_float4(0,0,0,0);
        v4f E1A, E2A, E3A, E1B, E2B, E3B;
        float4 SMA, SMB;
        E1A = E2A = E3A = E1B = E2B = E3B = (v4f){NEG_SENT, NEG_SENT, NEG_SENT, NEG_SENT};
        SMA = SMB = make_float4(0,0,0,0);
        if (act) {
            W2  = *(const float4*)(w2p + c0);
            W3  = *(const float4*)(w3p + c0);
            HH  = *(const float4*)(Hp + c0);
            E1A = __builtin_nontemporal_load((const v4f*)(e1p + baseA + c0));
            E1B = __builtin_nontemporal_load((const v4f*)(e1p + baseB + c0));
            E2A = __builtin_nontemporal_load((const v4f*)(e2p + baseA + c0));
            E2B = __builtin_nontemporal_load((const v4f*)(e2p + baseB + c0));
            E3A = __builtin_nontemporal_load((const v4f*)(e3p + baseA + c0));
            E3B = __builtin_nontemporal_load((const v4f*)(e3p + baseB + c0));
            SMA = *(const float4*)(sm + tgtA * C_N + c0);
            SMB = *(const float4*)(sm + tgtB * C_N + c0);
        }

        const float laA0 = (1.0f - ALPHA) * (c0     == tgtA) + ALPHA * SMA.x;
        const float laA1 = (1.0f - ALPHA) * (c0 + 1 == tgtA) + ALPHA * SMA.y;
        const float laA2 = (1.0f - ALPHA) * (c0 + 2 == tgtA) + ALPHA * SMA.z;
        const float laA3 = (1.0f - ALPHA) * (c0 + 3 == tgtA) + ALPHA * SMA.w;
        float s1A = __expf(E1A.x) + __expf(E1A.y) + __expf(E1A.z) + __expf(E1A.w);
        float s2A = W2.x * __expf(E2A.x) + W2.y * __expf(E2A.y)
                  + W2.z * __expf(E2A.z) + W2.w * __expf(E2A.w);
        float s3A = W3.x * __expf(E3A.x) + W3.y * __expf(E3A.y)
                  + W3.z * __expf(E3A.z) + W3.w * __expf(E3A.w);
        float dtA = laA0 * (E1A.x + E2A.x + E3A.x + HH.x)
                  + laA1 * (E1A.y + E2A.y + E3A.y + HH.y)
                  + laA2 * (E1A.z + E2A.z + E3A.z + HH.z)
                  + laA3 * (E1A.w + E2A.w + E3A.w + HH.w);
        const float laB0 = (1.0f - ALPHA) * (c0     == tgtB) + ALPHA * SMB.x;
        const float laB1 = (1.0f - ALPHA) * (c0 + 1 == tgtB) + ALPHA * SMB.y;
        const float laB2 = (1.0f - ALPHA) * (c0 + 2 == tgtB) + ALPHA * SMB.z;
        const float laB3 = (1.0f - ALPHA) * (c0 + 3 == tgtB) + ALPHA * SMB.w;
        float s1B = __expf(E1B.x) + __expf(E1B.y) + __expf(E1B.z) + __expf(E1B.w);
        float s2B = W2.x * __expf(E2B.x) + W2.y * __expf(E2B.y)
                  + W2.z * __expf(E2B.z) + W2.w * __expf(E2B.w);
        float s3B = W3.x * __expf(E3B.x) + W3.y * __expf(E3B.y)
                  + W3.z * __expf(E3B.z) + W3.w * __expf(E3B.w);
        float dtB = laB0 * (E1B.x + E2B.x + E3B.x + HH.x)
                  + laB1 * (E1B.y + E2B.y + E3B.y + HH.y)
                  + laB2 * (E1B.z + E2B.z + E3B.z + HH.z)
                  + laB3 * (E1B.w + E2B.w + E3B.w + HH.w);

        s1A = rowsum32(s1A);  s1B = rowsum32(s1B);
        s2A = rowsum32(s2A);  s2B = rowsum32(s2B);
        s3A = rowsum32(s3A);  s3B = rowsum32(s3B);
        dtA = rowsum32(dtA);  dtB = rowsum32(dtB);

        const float ceA = __logf(s1A * s2A * s3A) - dtA;
        const float ceB = __logf(s1B * s2B * s3B) - dtB;
        float lossAcc = own ? (ceA + ceB) : 0.f;
        const float lossW = __shfl(lossAcc, 16) + __shfl(lossAcc, 48);
        if (lane == 0) bl[wslot] = lossW;
        __syncthreads();
        if (threadIdx.x == 0)
            atomicAdd(&pl[bucket], bl[0] + bl[1] + bl[2] + bl[3]);
    } else {
        // ================= KL role: old_pred,output -> kl partial + dout rows =================
        const int gw = j * 4 + wslot;
        const int rowA = 4 * gw + half;
        const int rowB = 4 * gw + 2 + half;
        const int tgtA = target[rowA];
        const int tgtB = target[rowB];
        const int baseA = rowA * C_N;
        const int baseB = rowB * C_N;

        v4f OPA, OUA, OPB, OUB;
        OPA = OUA = OPB = OUB = (v4f){NEG_SENT, NEG_SENT, NEG_SENT, NEG_SENT};
        if (act) {
            OPA = __builtin_nontemporal_load((const v4f*)(opp + baseA + c0));
            OPB = __builtin_nontemporal_load((const v4f*)(opp + baseB + c0));
            OUA = __builtin_nontemporal_load((const v4f*)(outp + baseA + c0));
            OUB = __builtin_nontemporal_load((const v4f*)(outp + baseB + c0));
        }
        const float rcA = 1.0f / (float)counts[tgtA];
        const float rcB = 1.0f / (float)counts[tgtB];

        // pair A
        const float aA0 = OPA.x * 0.5f, aA1 = OPA.y * 0.5f, aA2 = OPA.z * 0.5f, aA3 = OPA.w * 0.5f;
        const float pA0 = __expf(aA0), pA1 = __expf(aA1), pA2 = __expf(aA2), pA3 = __expf(aA3);
        float ztA = pA0 + pA1 + pA2 + pA3;
        float bvA = OPA.x; int biA = c0;
        if (OPA.y > bvA) { bvA = OPA.y; biA = c0 + 1; }
        if (OPA.z > bvA) { bvA = OPA.z; biA = c0 + 2; }
        if (OPA.w > bvA) { bvA = OPA.w; biA = c0 + 3; }
        unsigned bbA = __float_as_uint(bvA);
        bbA = ((int)bbA < 0) ? ~bbA : (bbA | 0x80000000u);
        unsigned khiA = bbA, kloA = (unsigned)~biA;
        const float esA0 = OUA.x * rcA, esA1 = OUA.y * rcA, esA2 = OUA.z * rcA, esA3 = OUA.w * rcA;
        const float xA0 = esA0 * 0.5f, xA1 = esA1 * 0.5f, xA2 = esA2 * 0.5f, xA3 = esA3 * 0.5f;
        float zsA = __expf(xA0) + __expf(xA1) + __expf(xA2) + __expf(xA3);
        float DA  = pA0 * (aA0 - xA0) + pA1 * (aA1 - xA1) + pA2 * (aA2 - xA2) + pA3 * (aA3 - xA3);
        if (act) {
            v2f w0 = { esA0, esA1 };
            v2f w1 = { esA2, esA3 };
            __builtin_nontemporal_store(w0, (v2f*)(dout + 2 + baseA + c0));
            __builtin_nontemporal_store(w1, (v2f*)(dout + 2 + baseA + c0 + 2));
        }
        // pair B
        const float aB0 = OPB.x * 0.5f, aB1 = OPB.y * 0.5f, aB2 = OPB.z * 0.5f, aB3 = OPB.w * 0.5f;
        const float pB0 = __expf(aB0), pB1 = __expf(aB1), pB2 = __expf(aB2), pB3 = __expf(aB3);
        float ztB = pB0 + pB1 + pB2 + pB3;
        float bvB = OPB.x; int biB = c0;
        if (OPB.y > bvB) { bvB = OPB.y; biB = c0 + 1; }
        if (OPB.z > bvB) { bvB = OPB.z; biB = c0 + 2; }
        if (OPB.w > bvB) { bvB = OPB.w; biB = c0 + 3; }
        unsigned bbB = __float_as_uint(bvB);
        bbB = ((int)bbB < 0) ? ~bbB : (bbB | 0x80000000u);
        unsigned khiB = bbB, kloB = (unsigned)~biB;
        const float esB0 = OUB.x * rcB, esB1 = OUB.y * rcB, esB2 = OUB.z * rcB, esB3 = OUB.w * rcB;
        const float xB0 = esB0 * 0.5f, xB1 = esB1 * 0.5f, xB2 = esB2 * 0.5f, xB3 = esB3 * 0.5f;
        float zsB = __expf(xB0) + __expf(xB1) + __expf(xB2) + __expf(xB3);
        float DB  = pB0 * (aB0 - xB0) + pB1 * (aB1 - xB1) + pB2 * (aB2 - xB2) + pB3 * (aB3 - xB3);
        if (act) {
            v2f w0 = { esB0, esB1 };
            v2f w1 = { esB2, esB3 };
            __builtin_nontemporal_store(w0, (v2f*)(dout + 2 + baseB + c0));
            __builtin_nontemporal_store(w1, (v2f*)(dout + 2 + baseB + c0 + 2));
        }

        ztA = rowsum32(ztA);  ztB = rowsum32(ztB);
        zsA = rowsum32(zsA);  zsB = rowsum32(zsB);
        DA  = rowsum32(DA);   DB  = rowsum32(DB);
        rowamax32(khiA, kloA);
        rowamax32(khiB, kloB);

        const int miA = (int)~kloA;
        const int miB = (int)~kloB;
        const float rztA = 1.0f / ztA, rztB = 1.0f / ztB;
        const float klvA = DA * rztA + __logf(zsA * rztA);
        const float klvB = DB * rztB + __logf(zsB * rztB);
        const bool selA = own && (miA == tgtA);
        const bool selB = own && (miB == tgtB);
        float klAcc = (selA ? klvA : 0.f) + (selB ? klvB : 0.f);
        float nAcc  = (selA ? 1.f : 0.f) + (selB ? 1.f : 0.f);
        const float klW = __shfl(klAcc, 16) + __shfl(klAcc, 48);
        const float nW  = __shfl(nAcc, 16) + __shfl(nAcc, 48);
        if (lane == 0) { bk[wslot] = klW; bn[wslot] = nW; }
        __syncthreads();
        if (threadIdx.x == 0) {
            atomicAdd(&pk[bucket], bk[0] + bk[1] + bk[2] + bk[3]);
            atomicAdd(&pn[bucket], bn[0] + bn[1] + bn[2] + bn[3]);
        }
    }
}

// ---------- final: reduce 256 buckets ----------
__global__ void final_k(const float* __restrict__ pl, const float* __restrict__ pk,
                        const float* __restrict__ pn, float* __restrict__ dout) {
    __shared__ float sl[256], sk[256], sn[256];
    const int t = threadIdx.x;
    sl[t] = pl[t]; sk[t] = pk[t]; sn[t] = pn[t];
    __syncthreads();
    for (int s = 128; s; s >>= 1) {
        if (t < s) { sl[t] += sl[t + s]; sk[t] += sk[t + s]; sn[t] += sn[t + s]; }
        __syncthreads();
    }
    if (t == 0) {
        dout[0] = sl[0] / (float)B_N;
        const float kl = (sn[0] > 0.f) ? (sk[0] / fmaxf(sn[0], 1.f)) : 0.f;
        dout[1] = kl * (TEMP * TEMP) * 3.0f;
    }
}

extern "C" void kernel_launch(void* const* d_in, const int* in_sizes, int n_in,
                              void* d_out, int out_size, void* d_ws, size_t ws_size,
                              hipStream_t stream) {
    const int*   target = (const int*)  d_in[1];
    const float* cosf   = (const float*)d_in[2];
    const float* oldp   = (const float*)d_in[3];
    const float* e1     = (const float*)d_in[4];
    const float* e2     = (const float*)d_in[5];
    const float* e3     = (const float*)d_in[6];
    const float* outp   = (const float*)d_in[7];
    const float* prior  = (const float*)d_in[8];

    float* ws    = (float*)d_ws;
    float* sm    = ws;                  // [10000] (+16 pad)
    float* w2    = ws + 10016;          // [104]
    float* w3    = ws + 10120;          // [104]
    float* Ht    = ws + 10224;          // [104]
    int*   cnts  = (int*)(ws + 10328);  // [104]
    float* pl    = ws + 10432;          // [256]
    float* pk    = pl + 256;            // [256]
    float* pn    = pk + 256;            // [256]

    // zero cnts + pl/pk/pn in one shot (contiguous: 104 ints + 768 floats)
    hipMemsetAsync(cnts, 0, (104 + 768) * sizeof(float), stream);
    prep_k<<<261, 256, 0, stream>>>(cosf, prior, target, sm, w2, w3, Ht, cnts);
    main_k<<<NBLK, 256, 0, stream>>>(target, e1, e2, e3, oldp, outp,
                                     sm, w2, w3, Ht, cnts, (float*)d_out, pl, pk, pn);
    final_k<<<1, 256, 0, stream>>>(pl, pk, pn, (float*)d_out);
}